// Round 2
// baseline (312.162 us; speedup 1.0000x reference)
//
#include <hip/hip_runtime.h>
#include <hip/hip_bf16.h>

// GCN layer: out[b,n,o] = dis[b,n] * sum_m adj[b,n,m] * dis[b,m] * (x[b,m,:]@W[o,:] + bias[o])
// dis[b,n] = (rowsum(adj[b,n,:]) - adj[b,n,n])^-1/2
//
// R2 structure:
//  K1: per-row degree -> dis[b,n]  AND  adj_bf16 = bf16(adj) (fused; adj read once from HBM,
//      abf lands in L3 for K3)
//  K2: hT[o, b*2048+m] = dis[m] * (x@W^T + bias), bf16, o-major (k-contiguous for K3 B-frags)
//  K3: out = dis[n] * (adj_bf16 @ hT). LDS-FREE, BARRIER-FREE: both MFMA fragments are
//      16B k-contiguous runs -> direct global bf16x8 loads. batch = bx&7 pins each batch's
//      1MB hT slice to one XCD's L2. 512 blocks = 2 blocks/CU = 8 waves/CU, no syncthreads
//      so waves pipeline freely (no vmcnt(0) barrier drain).

#define BATCH 8
#define NN    2048
#define DIN   256
#define DOUT  256
#define RTOT  (BATCH * NN)   // 16384

typedef short  bf16x8  __attribute__((ext_vector_type(8)));
typedef short  short4v __attribute__((ext_vector_type(4)));
typedef float  f32x4   __attribute__((ext_vector_type(4)));

__device__ __forceinline__ short f2bf(float f) {
    union { float f; unsigned u; } v; v.f = f;
    unsigned r = v.u + 0x7fffu + ((v.u >> 16) & 1u);   // RNE
    return (short)(r >> 16);
}

// ---------------- K1: degrees -> dis, and adj -> bf16 ----------------
__global__ __launch_bounds__(256) void k_degree_cvt(const float* __restrict__ adj,
                                                    float* __restrict__ dis,
                                                    unsigned short* __restrict__ abf) {
    const int row = blockIdx.x;                 // 0..16383
    const int n = row & (NN - 1);
    const int tid = threadIdx.x;
    const float4* rp4 = (const float4*)(adj + (size_t)row * NN);
    unsigned short* op = abf + (size_t)row * NN;

    float s = 0.f;
#pragma unroll
    for (int i = 0; i < 2; i++) {
        float4 v = rp4[tid + i * 256];
        s += (v.x + v.y) + (v.z + v.w);
        short4v sv = { f2bf(v.x), f2bf(v.y), f2bf(v.z), f2bf(v.w) };
        *(short4v*)(op + 4 * (tid + i * 256)) = sv;
    }
#pragma unroll
    for (int off = 32; off; off >>= 1) s += __shfl_down(s, off);
    __shared__ float red[4];
    if ((tid & 63) == 0) red[tid >> 6] = s;
    __syncthreads();
    if (tid == 0) {
        float tot  = (red[0] + red[1]) + (red[2] + red[3]);
        float diag = ((const float*)rp4)[n];
        dis[row]   = rsqrtf(tot - diag);
    }
}

// ---------------- K2: projection, transposed + dis-folded ----------------
// hT[o, r] = dis[r] * (sum_d W[o,d] * x[r,d] + bias[o]);  M'=256(o), N'=16384(r), K=256
__global__ __launch_bounds__(256) void k_proj(const float* __restrict__ x,
                                              const float* __restrict__ W,
                                              const float* __restrict__ bias,
                                              const float* __restrict__ dis,
                                              unsigned short* __restrict__ hT) {
    const int mt  = blockIdx.y;           // 0..1   (o-tile of 128)
    const int nt  = blockIdx.x;           // 0..127 (r-tile of 128)
    const int tid = threadIdx.x;
    const int w = tid >> 6, lane = tid & 63;
    const int wr = w >> 1, wc = w & 1;
    const int l16 = lane & 15, quad = lane >> 4;

    __shared__ short As[128][32];   // W rows (o), k-contig
    __shared__ short Bs[128][32];   // x rows (r), k-contig

    f32x4 acc[4][4];
#pragma unroll
    for (int i = 0; i < 4; i++)
#pragma unroll
        for (int j = 0; j < 4; j++) acc[i][j] = (f32x4){0.f, 0.f, 0.f, 0.f};

    const float4* Wf4 = (const float4*)(W + (size_t)mt * 128 * DIN);
    const float4* Xf4 = (const float4*)(x + (size_t)nt * 128 * DIN);

    for (int kk = 0; kk < DIN / 32; kk++) {
        const int k0 = kk * 32;
        __syncthreads();
#pragma unroll
        for (int it = 0; it < 4; it++) {
            int idx = tid + it * 256;           // 128 rows x 8 float4
            int r = idx >> 3, c = idx & 7;
            float4 va = Wf4[(size_t)r * (DIN / 4) + (k0 >> 2) + c];
            float4 vb = Xf4[(size_t)r * (DIN / 4) + (k0 >> 2) + c];
            short4v sa = { f2bf(va.x), f2bf(va.y), f2bf(va.z), f2bf(va.w) };
            short4v sb = { f2bf(vb.x), f2bf(vb.y), f2bf(vb.z), f2bf(vb.w) };
            *(short4v*)&As[r][c * 4] = sa;
            *(short4v*)&Bs[r][c * 4] = sb;
        }
        __syncthreads();
        bf16x8 af[4], bfv[4];
#pragma unroll
        for (int i = 0; i < 4; i++) af[i]  = *(bf16x8*)&As[wr * 64 + i * 16 + l16][quad * 8];
#pragma unroll
        for (int j = 0; j < 4; j++) bfv[j] = *(bf16x8*)&Bs[wc * 64 + j * 16 + l16][quad * 8];
#pragma unroll
        for (int i = 0; i < 4; i++)
#pragma unroll
            for (int j = 0; j < 4; j++)
                acc[i][j] = __builtin_amdgcn_mfma_f32_16x16x32_bf16(af[i], bfv[j], acc[i][j], 0, 0, 0);
    }

#pragma unroll
    for (int i = 0; i < 4; i++) {
        const int orow_base = mt * 128 + wr * 64 + i * 16 + quad * 4;
#pragma unroll
        for (int r = 0; r < 4; r++) {
            const int orow = orow_base + r;
            const float bb = bias[orow];
#pragma unroll
            for (int j = 0; j < 4; j++) {
                const int col = nt * 128 + wc * 64 + j * 16 + l16;
                float v = (acc[i][j][r] + bb) * dis[col];
                hT[(size_t)orow * RTOT + col] = (unsigned short)f2bf(v);
            }
        }
    }
}

// ---------------- K3: out = dis[n] * (abf @ hT), LDS-free, barrier-free ----------------
// Per batch: M=2048(n), K=2048(m), N=256(o). Block tile 64x128 (4 waves of 64x32).
// Grid 512: bx&7=batch (XCD affinity), (bx>>3)&31=mtile, bx>>8=ctile.
__global__ __launch_bounds__(256, 2) void k_main(const unsigned short* __restrict__ abf,
                                                 const unsigned short* __restrict__ hT,
                                                 const float* __restrict__ dis,
                                                 float* __restrict__ out) {
    const int bx    = blockIdx.x;
    const int b     = bx & 7;
    const int mtile = (bx >> 3) & 31;
    const int ctile = bx >> 8;            // 0..1
    const int n0    = mtile * 64;
    const int tid = threadIdx.x;
    const int w = tid >> 6, lane = tid & 63;
    const int l16 = lane & 15, quad = lane >> 4;
    const int o0 = ctile * 128 + w * 32;  // this wave's 32-col range

    // Per-lane stream base pointers (k-contiguous 16B frags).
    const unsigned short* aP[4];
#pragma unroll
    for (int i = 0; i < 4; i++)
        aP[i] = abf + ((size_t)b * NN + n0 + i * 16 + l16) * NN + quad * 8;
    const unsigned short* bP[2];
#pragma unroll
    for (int j = 0; j < 2; j++)
        bP[j] = hT + (size_t)(o0 + j * 16 + l16) * RTOT + b * NN + quad * 8;

    f32x4 acc[4][2];
#pragma unroll
    for (int i = 0; i < 4; i++)
#pragma unroll
        for (int j = 0; j < 2; j++) acc[i][j] = (f32x4){0.f, 0.f, 0.f, 0.f};

#pragma unroll 4
    for (int kk = 0; kk < NN / 32; kk++) {
        const int ko = kk * 32;
        bf16x8 af[4], bfv[2];
#pragma unroll
        for (int i = 0; i < 4; i++) af[i]  = *(const bf16x8*)(aP[i] + ko);
#pragma unroll
        for (int j = 0; j < 2; j++) bfv[j] = *(const bf16x8*)(bP[j] + ko);
#pragma unroll
        for (int i = 0; i < 4; i++)
#pragma unroll
            for (int j = 0; j < 2; j++)
                acc[i][j] = __builtin_amdgcn_mfma_f32_16x16x32_bf16(af[i], bfv[j], acc[i][j], 0, 0, 0);
    }

    const float* disb = dis + (size_t)b * NN;
#pragma unroll
    for (int i = 0; i < 4; i++) {
#pragma unroll
        for (int r = 0; r < 4; r++) {
            const int nrow = n0 + i * 16 + quad * 4 + r;
            const float dn = disb[nrow];
#pragma unroll
            for (int j = 0; j < 2; j++) {
                const int ocol = o0 + j * 16 + l16;
                out[((size_t)b * NN + nrow) * DOUT + ocol] = dn * acc[i][j][r];
            }
        }
    }
}

extern "C" void kernel_launch(void* const* d_in, const int* in_sizes, int n_in,
                              void* d_out, int out_size, void* d_ws, size_t ws_size,
                              hipStream_t stream) {
    const float* x    = (const float*)d_in[0];
    const float* adj  = (const float*)d_in[1];
    const float* W    = (const float*)d_in[2];
    const float* bias = (const float*)d_in[3];
    float* out = (float*)d_out;

    float* dis = (float*)d_ws;                                         // 64 KB
    unsigned short* hT  = (unsigned short*)((char*)d_ws + 65536);      // 8 MB  [256][16384]
    unsigned short* abf = (unsigned short*)((char*)d_ws + 65536 + (size_t)RTOT * DOUT * 2); // 67 MB

    k_degree_cvt<<<RTOT, 256, 0, stream>>>(adj, dis, abf);
    k_proj<<<dim3(128, 2), 256, 0, stream>>>(x, W, bias, dis, hT);
    k_main<<<512, 256, 0, stream>>>(abf, hT, dis, out);
}

// Round 3
// 289.273 us; speedup vs baseline: 1.0791x; 1.0791x over previous
//
#include <hip/hip_runtime.h>
#include <hip/hip_bf16.h>

// GCN layer: out[b,n,o] = dis[b,n] * sum_m adj[b,n,m] * dis[b,m] * (x[b,m,:]@W[o,:] + bias[o])
//
// R3 changes vs R2 (k_main was latency-bound at 92us, all pipes <8%):
//  1. PAD scratch row strides off power-of-2: abf rows 2048 -> 2080 elems (4160B),
//     hT row stride 16384 -> 16416 (32832B). R2's per-lane fragment gathers strided
//     exactly 4KB/32KB between lanes -> L2 channel aliasing serialized every load.
//  2. Explicit register triple-buffering (prefetch distance 2) in k_main: 18 loads
//     in flight per wave while 24 MFMAs issue, instead of compiler's 1-iter-deep
//     load;wait;mfma (VGPR_Count=48 showed no pipelining).

#define BATCH 8
#define NN    2048
#define DIN   256
#define DOUT  256
#define RTOT  (BATCH * NN)   // 16384
#define AP    (NN + 32)      // 2080  padded abf row stride (elems)
#define HP    (RTOT + 32)    // 16416 padded hT row stride (elems)

typedef short  bf16x8  __attribute__((ext_vector_type(8)));
typedef short  short4v __attribute__((ext_vector_type(4)));
typedef float  f32x4   __attribute__((ext_vector_type(4)));

__device__ __forceinline__ short f2bf(float f) {
    union { float f; unsigned u; } v; v.f = f;
    unsigned r = v.u + 0x7fffu + ((v.u >> 16) & 1u);   // RNE
    return (short)(r >> 16);
}

// ---------------- K1: degrees -> dis, and adj -> bf16 (padded rows) ----------------
__global__ __launch_bounds__(256) void k_degree_cvt(const float* __restrict__ adj,
                                                    float* __restrict__ dis,
                                                    unsigned short* __restrict__ abf) {
    const int row = blockIdx.x;                 // 0..16383
    const int n = row & (NN - 1);
    const int tid = threadIdx.x;
    const float4* rp4 = (const float4*)(adj + (size_t)row * NN);
    unsigned short* op = abf + (size_t)row * AP;

    float s = 0.f;
#pragma unroll
    for (int i = 0; i < 2; i++) {
        float4 v = rp4[tid + i * 256];
        s += (v.x + v.y) + (v.z + v.w);
        short4v sv = { f2bf(v.x), f2bf(v.y), f2bf(v.z), f2bf(v.w) };
        *(short4v*)(op + 4 * (tid + i * 256)) = sv;
    }
#pragma unroll
    for (int off = 32; off; off >>= 1) s += __shfl_down(s, off);
    __shared__ float red[4];
    if ((tid & 63) == 0) red[tid >> 6] = s;
    __syncthreads();
    if (tid == 0) {
        float tot  = (red[0] + red[1]) + (red[2] + red[3]);
        float diag = ((const float*)rp4)[n];
        dis[row]   = rsqrtf(tot - diag);
    }
}

// ---------------- K2: projection, transposed + dis-folded, padded hT ----------------
__global__ __launch_bounds__(256) void k_proj(const float* __restrict__ x,
                                              const float* __restrict__ W,
                                              const float* __restrict__ bias,
                                              const float* __restrict__ dis,
                                              unsigned short* __restrict__ hT) {
    const int mt  = blockIdx.y;           // 0..1   (o-tile of 128)
    const int nt  = blockIdx.x;           // 0..127 (r-tile of 128)
    const int tid = threadIdx.x;
    const int w = tid >> 6, lane = tid & 63;
    const int wr = w >> 1, wc = w & 1;
    const int l16 = lane & 15, quad = lane >> 4;

    __shared__ short As[128][32];
    __shared__ short Bs[128][32];

    f32x4 acc[4][4];
#pragma unroll
    for (int i = 0; i < 4; i++)
#pragma unroll
        for (int j = 0; j < 4; j++) acc[i][j] = (f32x4){0.f, 0.f, 0.f, 0.f};

    const float4* Wf4 = (const float4*)(W + (size_t)mt * 128 * DIN);
    const float4* Xf4 = (const float4*)(x + (size_t)nt * 128 * DIN);

    for (int kk = 0; kk < DIN / 32; kk++) {
        const int k0 = kk * 32;
        __syncthreads();
#pragma unroll
        for (int it = 0; it < 4; it++) {
            int idx = tid + it * 256;
            int r = idx >> 3, c = idx & 7;
            float4 va = Wf4[(size_t)r * (DIN / 4) + (k0 >> 2) + c];
            float4 vb = Xf4[(size_t)r * (DIN / 4) + (k0 >> 2) + c];
            short4v sa = { f2bf(va.x), f2bf(va.y), f2bf(va.z), f2bf(va.w) };
            short4v sb = { f2bf(vb.x), f2bf(vb.y), f2bf(vb.z), f2bf(vb.w) };
            *(short4v*)&As[r][c * 4] = sa;
            *(short4v*)&Bs[r][c * 4] = sb;
        }
        __syncthreads();
        bf16x8 af[4], bfv[4];
#pragma unroll
        for (int i = 0; i < 4; i++) af[i]  = *(bf16x8*)&As[wr * 64 + i * 16 + l16][quad * 8];
#pragma unroll
        for (int j = 0; j < 4; j++) bfv[j] = *(bf16x8*)&Bs[wc * 64 + j * 16 + l16][quad * 8];
#pragma unroll
        for (int i = 0; i < 4; i++)
#pragma unroll
            for (int j = 0; j < 4; j++)
                acc[i][j] = __builtin_amdgcn_mfma_f32_16x16x32_bf16(af[i], bfv[j], acc[i][j], 0, 0, 0);
    }

#pragma unroll
    for (int i = 0; i < 4; i++) {
        const int orow_base = mt * 128 + wr * 64 + i * 16 + quad * 4;
#pragma unroll
        for (int r = 0; r < 4; r++) {
            const int orow = orow_base + r;
            const float bb = bias[orow];
#pragma unroll
            for (int j = 0; j < 4; j++) {
                const int col = nt * 128 + wc * 64 + j * 16 + l16;
                float v = (acc[i][j][r] + bb) * dis[col];
                hT[(size_t)orow * HP + col] = (unsigned short)f2bf(v);
            }
        }
    }
}

// ---------------- K3: out = dis[n] * (abf @ hT), LDS-free, triple-buffered ----------------
// Per batch: M=2048(n), K=2048(m), N=256(o). Block tile 64x128 (4 waves of 64x32).
// Grid 512: bx&7=batch (XCD affinity), (bx>>3)&31=mtile, bx>>8=otile.
__global__ __launch_bounds__(256, 2) void k_main(const unsigned short* __restrict__ abf,
                                                 const unsigned short* __restrict__ hT,
                                                 const float* __restrict__ dis,
                                                 float* __restrict__ out) {
    const int bx    = blockIdx.x;
    const int b     = bx & 7;
    const int mtile = (bx >> 3) & 31;
    const int ctile = bx >> 8;            // 0..1
    const int n0    = mtile * 64;
    const int tid = threadIdx.x;
    const int w = tid >> 6, lane = tid & 63;
    const int l16 = lane & 15, quad = lane >> 4;
    const int o0 = ctile * 128 + w * 32;

    const unsigned short* aP[4];
#pragma unroll
    for (int i = 0; i < 4; i++)
        aP[i] = abf + (size_t)(b * NN + n0 + i * 16 + l16) * AP + quad * 8;
    const unsigned short* bP[2];
#pragma unroll
    for (int j = 0; j < 2; j++)
        bP[j] = hT + (size_t)(o0 + j * 16 + l16) * HP + b * NN + quad * 8;

    f32x4 acc[4][2];
#pragma unroll
    for (int i = 0; i < 4; i++)
#pragma unroll
        for (int j = 0; j < 2; j++) acc[i][j] = (f32x4){0.f, 0.f, 0.f, 0.f};

    bf16x8 af[3][4], bfv[3][2];

#define LOADSET(s, k) do {                                              \
        const int _ko = (k) * 32;                                       \
        _Pragma("unroll")                                               \
        for (int _i = 0; _i < 4; _i++) af[s][_i]  = *(const bf16x8*)(aP[_i] + _ko); \
        _Pragma("unroll")                                               \
        for (int _j = 0; _j < 2; _j++) bfv[s][_j] = *(const bf16x8*)(bP[_j] + _ko); \
    } while (0)

#define MFMASET(s) do {                                                 \
        _Pragma("unroll")                                               \
        for (int _i = 0; _i < 4; _i++)                                  \
            _Pragma("unroll")                                           \
            for (int _j = 0; _j < 2; _j++)                              \
                acc[_i][_j] = __builtin_amdgcn_mfma_f32_16x16x32_bf16(  \
                    af[s][_i], bfv[s][_j], acc[_i][_j], 0, 0, 0);       \
    } while (0)

    LOADSET(0, 0);
    LOADSET(1, 1);
    // kk = 3t .. 3t+2 for t=0..20 covers k=0..62; loads run ahead to k=64
    // (k=64 reads land in the 32-elem row pad -- in-bounds, never consumed).
    for (int t = 0; t < 21; t++) {
        const int kk = 3 * t;
        LOADSET(2, kk + 2);
        MFMASET(0);
        LOADSET(0, kk + 3);
        MFMASET(1);
        LOADSET(1, kk + 4);
        MFMASET(2);
    }
    MFMASET(0);   // k = 63

#undef LOADSET
#undef MFMASET

    const float* disb = dis + (size_t)b * NN;
#pragma unroll
    for (int i = 0; i < 4; i++) {
#pragma unroll
        for (int r = 0; r < 4; r++) {
            const int nrow = n0 + i * 16 + quad * 4 + r;
            const float dn = disb[nrow];
#pragma unroll
            for (int j = 0; j < 2; j++) {
                const int ocol = o0 + j * 16 + l16;
                out[((size_t)b * NN + nrow) * DOUT + ocol] = dn * acc[i][j][r];
            }
        }
    }
}

extern "C" void kernel_launch(void* const* d_in, const int* in_sizes, int n_in,
                              void* d_out, int out_size, void* d_ws, size_t ws_size,
                              hipStream_t stream) {
    const float* x    = (const float*)d_in[0];
    const float* adj  = (const float*)d_in[1];
    const float* W    = (const float*)d_in[2];
    const float* bias = (const float*)d_in[3];
    float* out = (float*)d_out;

    float* dis = (float*)d_ws;                                             // 64 KB
    unsigned short* hT  = (unsigned short*)((char*)d_ws + 65536);          // 256*16416*2 = 8.4 MB
    unsigned short* abf = (unsigned short*)((char*)d_ws + 65536 + (size_t)DOUT * HP * 2); // 16384*2080*2 = 68 MB

    k_degree_cvt<<<RTOT, 256, 0, stream>>>(adj, dis, abf);
    k_proj<<<dim3(128, 2), 256, 0, stream>>>(x, W, bias, dis, hT);
    k_main<<<512, 256, 0, stream>>>(abf, hT, dis, out);
}

// Round 4
// 263.024 us; speedup vs baseline: 1.1868x; 1.0998x over previous
//
#include <hip/hip_runtime.h>
#include <hip/hip_bf16.h>

// GCN layer: out[b,n,o] = dis[b,n] * sum_m adj[b,n,m] * dis[b,m] * (x[b,m,:]@W[o,:] + bias[o])
//
// R4: k_main rebuilt as m97-style LDS-staged GEMM. R3's LDS-free k_main was
// L3-BW-bound on 4x-redundant per-wave A-fragment loads (~800MB issued, ~70us).
// Now: A-tile staged once per block via global_load_lds (width=16), B-tile too;
// [rows][32] 64B-row LDS layout (m97-proven); double-buffered, ONE barrier per
// window (stage k+1 issued after the barrier overlaps window k's ds_read+MFMA;
// residual drain hidden by 2 blocks/CU).

#define BATCH 8
#define NN    2048
#define DIN   256
#define DOUT  256
#define RTOT  (BATCH * NN)   // 16384
#define AP    (NN + 32)      // 2080  padded abf row stride (elems)
#define HP    (RTOT + 32)    // 16416 padded hT row stride (elems)

typedef short  bf16x8  __attribute__((ext_vector_type(8)));
typedef short  short4v __attribute__((ext_vector_type(4)));
typedef float  f32x4   __attribute__((ext_vector_type(4)));

__device__ __forceinline__ short f2bf(float f) {
    union { float f; unsigned u; } v; v.f = f;
    unsigned r = v.u + 0x7fffu + ((v.u >> 16) & 1u);   // RNE
    return (short)(r >> 16);
}

__device__ __forceinline__ void gl_lds16(const unsigned short* g, unsigned short* l) {
    __builtin_amdgcn_global_load_lds(
        (const __attribute__((address_space(1))) unsigned int*)g,
        (__attribute__((address_space(3))) unsigned int*)l, 16, 0, 0);
}

// ---------------- K1: degrees -> dis, and adj -> bf16 (padded rows) ----------------
__global__ __launch_bounds__(256) void k_degree_cvt(const float* __restrict__ adj,
                                                    float* __restrict__ dis,
                                                    unsigned short* __restrict__ abf) {
    const int row = blockIdx.x;                 // 0..16383
    const int n = row & (NN - 1);
    const int tid = threadIdx.x;
    const float4* rp4 = (const float4*)(adj + (size_t)row * NN);
    unsigned short* op = abf + (size_t)row * AP;

    float s = 0.f;
#pragma unroll
    for (int i = 0; i < 2; i++) {
        float4 v = rp4[tid + i * 256];
        s += (v.x + v.y) + (v.z + v.w);
        short4v sv = { f2bf(v.x), f2bf(v.y), f2bf(v.z), f2bf(v.w) };
        *(short4v*)(op + 4 * (tid + i * 256)) = sv;
    }
#pragma unroll
    for (int off = 32; off; off >>= 1) s += __shfl_down(s, off);
    __shared__ float red[4];
    if ((tid & 63) == 0) red[tid >> 6] = s;
    __syncthreads();
    if (tid == 0) {
        float tot  = (red[0] + red[1]) + (red[2] + red[3]);
        float diag = ((const float*)rp4)[n];
        dis[row]   = rsqrtf(tot - diag);
    }
}

// ---------------- K2: projection, transposed + dis-folded, padded hT ----------------
__global__ __launch_bounds__(256) void k_proj(const float* __restrict__ x,
                                              const float* __restrict__ W,
                                              const float* __restrict__ bias,
                                              const float* __restrict__ dis,
                                              unsigned short* __restrict__ hT) {
    const int mt  = blockIdx.y;           // 0..1   (o-tile of 128)
    const int nt  = blockIdx.x;           // 0..127 (r-tile of 128)
    const int tid = threadIdx.x;
    const int w = tid >> 6, lane = tid & 63;
    const int wr = w >> 1, wc = w & 1;
    const int l16 = lane & 15, quad = lane >> 4;

    __shared__ short As[128][32];
    __shared__ short Bs[128][32];

    f32x4 acc[4][4];
#pragma unroll
    for (int i = 0; i < 4; i++)
#pragma unroll
        for (int j = 0; j < 4; j++) acc[i][j] = (f32x4){0.f, 0.f, 0.f, 0.f};

    const float4* Wf4 = (const float4*)(W + (size_t)mt * 128 * DIN);
    const float4* Xf4 = (const float4*)(x + (size_t)nt * 128 * DIN);

    for (int kk = 0; kk < DIN / 32; kk++) {
        const int k0 = kk * 32;
        __syncthreads();
#pragma unroll
        for (int it = 0; it < 4; it++) {
            int idx = tid + it * 256;
            int r = idx >> 3, c = idx & 7;
            float4 va = Wf4[(size_t)r * (DIN / 4) + (k0 >> 2) + c];
            float4 vb = Xf4[(size_t)r * (DIN / 4) + (k0 >> 2) + c];
            short4v sa = { f2bf(va.x), f2bf(va.y), f2bf(va.z), f2bf(va.w) };
            short4v sb = { f2bf(vb.x), f2bf(vb.y), f2bf(vb.z), f2bf(vb.w) };
            *(short4v*)&As[r][c * 4] = sa;
            *(short4v*)&Bs[r][c * 4] = sb;
        }
        __syncthreads();
        bf16x8 af[4], bfv[4];
#pragma unroll
        for (int i = 0; i < 4; i++) af[i]  = *(bf16x8*)&As[wr * 64 + i * 16 + l16][quad * 8];
#pragma unroll
        for (int j = 0; j < 4; j++) bfv[j] = *(bf16x8*)&Bs[wc * 64 + j * 16 + l16][quad * 8];
#pragma unroll
        for (int i = 0; i < 4; i++)
#pragma unroll
            for (int j = 0; j < 4; j++)
                acc[i][j] = __builtin_amdgcn_mfma_f32_16x16x32_bf16(af[i], bfv[j], acc[i][j], 0, 0, 0);
    }

#pragma unroll
    for (int i = 0; i < 4; i++) {
        const int orow_base = mt * 128 + wr * 64 + i * 16 + quad * 4;
#pragma unroll
        for (int r = 0; r < 4; r++) {
            const int orow = orow_base + r;
            const float bb = bias[orow];
#pragma unroll
            for (int j = 0; j < 4; j++) {
                const int col = nt * 128 + wc * 64 + j * 16 + l16;
                float v = (acc[i][j][r] + bb) * dis[col];
                hT[(size_t)orow * HP + col] = (unsigned short)f2bf(v);
            }
        }
    }
}

// ---------------- K3: out = dis[n] * (abf @ hT), LDS-staged, double-buffered ----------------
// Per batch: M=2048(n), K=2048(m), N=256(o). Block tile 64x128, BK=32.
// 4 waves, each 64(n) x 32(o): A-frags shared via LDS (4x dedup vs R3).
// Grid 512: bx&7=batch (XCD L2 affinity for hT), (bx>>3)&31=mtile, bx>>8=ctile.
__global__ __launch_bounds__(256, 2) void k_main(const unsigned short* __restrict__ abf,
                                                 const unsigned short* __restrict__ hT,
                                                 const float* __restrict__ dis,
                                                 float* __restrict__ out) {
    const int bx    = blockIdx.x;
    const int b     = bx & 7;
    const int mtile = (bx >> 3) & 31;
    const int ctile = bx >> 8;            // 0..1
    const int n0    = mtile * 64;
    const int tid  = threadIdx.x;
    const int w    = tid >> 6, lane = tid & 63;
    const int l16  = lane & 15, quad = lane >> 4;
    const int lr   = lane >> 2;           // 0..15 (staging row-within-group)
    const int lc   = (lane & 3) * 8;      // 0,8,16,24 (staging elem offset)

    __shared__ short As[2][64][32];       // adj rows(n) x k, bf16; 64B rows
    __shared__ short Bs[2][128][32];      // hT rows(o) x k, bf16

    // Staging source bases (per-lane), advanced by k each window:
    // A: wave w stages rows w*16 + lr; B: wave w stages rows w*32 + t*16 + lr (t=0,1).
    const unsigned short* agp = abf + (size_t)(b * NN + n0 + w * 16 + lr) * AP + lc;
    const unsigned short* bgp0 = hT + (size_t)(ctile * 128 + w * 32 + lr) * HP + b * NN + lc;
    const unsigned short* bgp1 = bgp0 + (size_t)16 * HP;
    // LDS dest bases (wave-uniform).
    unsigned short* alp[2] = { (unsigned short*)&As[0][w * 16][0], (unsigned short*)&As[1][w * 16][0] };
    unsigned short* blp0[2] = { (unsigned short*)&Bs[0][w * 32][0], (unsigned short*)&Bs[1][w * 32][0] };
    unsigned short* blp1[2] = { (unsigned short*)&Bs[0][w * 32 + 16][0], (unsigned short*)&Bs[1][w * 32 + 16][0] };

    f32x4 acc[4][2];
#pragma unroll
    for (int i = 0; i < 4; i++)
#pragma unroll
        for (int j = 0; j < 2; j++) acc[i][j] = (f32x4){0.f, 0.f, 0.f, 0.f};

    // Prologue: stage window 0 into buffer 0.
    gl_lds16(agp, alp[0]);
    gl_lds16(bgp0, blp0[0]);
    gl_lds16(bgp1, blp1[0]);

    for (int kk = 0; kk < NN / 32; kk++) {
        const int cur = kk & 1, nxt = cur ^ 1;
        __syncthreads();   // full drain: window-kk staging complete; prev ds_reads retired
        if (kk < NN / 32 - 1) {
            const int ko = (kk + 1) * 32;
            gl_lds16(agp + ko, alp[nxt]);
            gl_lds16(bgp0 + ko, blp0[nxt]);
            gl_lds16(bgp1 + ko, blp1[nxt]);
        }
        bf16x8 af[4], bfv[2];
#pragma unroll
        for (int i = 0; i < 4; i++) af[i]  = *(bf16x8*)&As[cur][i * 16 + l16][quad * 8];
#pragma unroll
        for (int j = 0; j < 2; j++) bfv[j] = *(bf16x8*)&Bs[cur][w * 32 + j * 16 + l16][quad * 8];
#pragma unroll
        for (int i = 0; i < 4; i++)
#pragma unroll
            for (int j = 0; j < 2; j++)
                acc[i][j] = __builtin_amdgcn_mfma_f32_16x16x32_bf16(af[i], bfv[j], acc[i][j], 0, 0, 0);
    }

    const float* disb = dis + (size_t)b * NN;
#pragma unroll
    for (int i = 0; i < 4; i++) {
#pragma unroll
        for (int r = 0; r < 4; r++) {
            const int nrow = n0 + i * 16 + quad * 4 + r;
            const float dn = disb[nrow];
#pragma unroll
            for (int j = 0; j < 2; j++) {
                const int ocol = ctile * 128 + w * 32 + j * 16 + l16;
                out[((size_t)b * NN + nrow) * DOUT + ocol] = dn * acc[i][j][r];
            }
        }
    }
}

extern "C" void kernel_launch(void* const* d_in, const int* in_sizes, int n_in,
                              void* d_out, int out_size, void* d_ws, size_t ws_size,
                              hipStream_t stream) {
    const float* x    = (const float*)d_in[0];
    const float* adj  = (const float*)d_in[1];
    const float* W    = (const float*)d_in[2];
    const float* bias = (const float*)d_in[3];
    float* out = (float*)d_out;

    float* dis = (float*)d_ws;                                             // 64 KB
    unsigned short* hT  = (unsigned short*)((char*)d_ws + 65536);          // 256*16416*2 = 8.4 MB
    unsigned short* abf = (unsigned short*)((char*)d_ws + 65536 + (size_t)DOUT * HP * 2); // 68 MB

    k_degree_cvt<<<RTOT, 256, 0, stream>>>(adj, dis, abf);
    k_proj<<<dim3(128, 2), 256, 0, stream>>>(x, W, bias, dis, hT);
    k_main<<<512, 256, 0, stream>>>(abf, hT, dis, out);
}